// Round 18
// baseline (157.626 us; speedup 1.0000x reference)
//
#include <hip/hip_runtime.h>

// ---------------------------------------------------------------------------
// Linformer self-attention, fp32 I/O, fp16 MFMA internally, MI355X (gfx950)
// b=4 n=4096 d=1024 h=16 dh=64 k=256  (no 1/sqrt(dh) scale per reference)
//
// Round 18: r17 (best, 155.8) + midphase: gemm_q and stage1_partial merged
// into ONE launch (they are data-independent) when ws_size permits moving
// the stage1 partials out of the Qh region. Runtime ws_size check; exact
// r17 serial fallback otherwise. All kernel bodies verified unchanged.
// ---------------------------------------------------------------------------

typedef __fp16 f16x8 __attribute__((ext_vector_type(8)));
typedef __fp16 f16x2 __attribute__((ext_vector_type(2)));
typedef float fl4 __attribute__((ext_vector_type(4)));
typedef float f32x4 __attribute__((ext_vector_type(4)));
typedef unsigned int u32x2 __attribute__((ext_vector_type(2)));
typedef unsigned int u32x4 __attribute__((ext_vector_type(4)));

#define MFMA16(a, b, c) __builtin_amdgcn_mfma_f32_16x16x32_f16((a), (b), (c), 0, 0, 0)

__device__ __forceinline__ unsigned int pk2u(float a, float b) {
  f16x2 p = __builtin_amdgcn_cvt_pkrtz(a, b);  // low = a, high = b
  return __builtin_bit_cast(unsigned int, p);
}

__device__ __forceinline__ f16x8 pk8(fl4 a, fl4 b) {
  f16x2 p0 = __builtin_amdgcn_cvt_pkrtz(a[0], a[1]);
  f16x2 p1 = __builtin_amdgcn_cvt_pkrtz(a[2], a[3]);
  f16x2 p2 = __builtin_amdgcn_cvt_pkrtz(b[0], b[1]);
  f16x2 p3 = __builtin_amdgcn_cvt_pkrtz(b[2], b[3]);
  f16x8 r;
  r[0] = p0[0]; r[1] = p0[1]; r[2] = p1[0]; r[3] = p1[1];
  r[4] = p2[0]; r[5] = p2[1]; r[6] = p3[0]; r[7] = p3[1];
  return r;
}

__device__ __forceinline__ void gload_lds16(const __fp16* g, void* lds_base) {
  __builtin_amdgcn_global_load_lds(
      (const __attribute__((address_space(1))) void*)g,
      (__attribute__((address_space(3))) void*)lds_base, 16, 0, 0);
}

// 128B-row tile fragment read: logical 16B chunk `ch` of `row`
__device__ __forceinline__ f16x8 rd128(const __fp16* base, int row, int ch) {
  return *(const f16x8*)((const char*)base + row * 128 +
                         ((ch ^ (row & 7)) * 16));
}

// ---------------------------------------------------------------------------
// prep: one launch. Blocks [0,8192): xprep (X f32 -> Xf16 + XT f16).
// [8192,11264): 3x W 1024x1024 transpose+cvt. [11264,13312): 2x proj
// 4096x256 transpose+cvt.
// ---------------------------------------------------------------------------
__device__ __forceinline__ void tr_cvt_body(
    float* tile, const float* in, __fp16* out, int R, int C, int bx, int by) {
  const int t = threadIdx.x;
  const int c0 = bx * 32, r0 = by * 32;
  {
    const int r = t >> 3, cg = (t & 7) * 4;
    fl4 v = *(const fl4*)(in + (size_t)(r0 + r) * C + c0 + cg);
    tile[r * 33 + cg] = v[0]; tile[r * 33 + cg + 1] = v[1];
    tile[r * 33 + cg + 2] = v[2]; tile[r * 33 + cg + 3] = v[3];
  }
  __syncthreads();
  {
    const int cc = t >> 3, rg = (t & 7) * 4;
    u32x2 p;
    p[0] = pk2u(tile[(rg + 0) * 33 + cc], tile[(rg + 1) * 33 + cc]);
    p[1] = pk2u(tile[(rg + 2) * 33 + cc], tile[(rg + 3) * 33 + cc]);
    *(u32x2*)(out + (size_t)(c0 + cc) * R + r0 + rg) = p;
  }
}

__global__ __launch_bounds__(256) void prep(
    const float* __restrict__ X, __fp16* __restrict__ Xf,
    __fp16* __restrict__ XT,
    const float* __restrict__ Wq, const float* __restrict__ Wk,
    const float* __restrict__ Wv, __fp16* __restrict__ WqT,
    __fp16* __restrict__ WkT, __fp16* __restrict__ WvT,
    const float* __restrict__ pk, const float* __restrict__ pv,
    __fp16* __restrict__ pkT, __fp16* __restrict__ pvT) {
  __shared__ float tile[32 * 65];
  const int id = blockIdx.x;
  const int t = threadIdx.x;
  if (id < 8192) {
    // xprep: 32n x 64d tile
    const int n0 = (id & 127) * 32, d0 = ((id >> 7) & 15) * 64, b = id >> 11;
    const float* src = X + ((size_t)b * 4096 + n0) * 1024 + d0;
    {
      const int r = t >> 3, cg = (t & 7) * 8;
      fl4 v0 = *(const fl4*)(src + (size_t)r * 1024 + cg);
      fl4 v1 = *(const fl4*)(src + (size_t)r * 1024 + cg + 4);
      *(f16x8*)(Xf + ((size_t)b * 4096 + n0 + r) * 1024 + d0 + cg) = pk8(v0, v1);
#pragma unroll
      for (int j = 0; j < 4; ++j) {
        tile[r * 65 + cg + j] = v0[j];
        tile[r * 65 + cg + 4 + j] = v1[j];
      }
    }
    __syncthreads();
    {
      const int d = t >> 2, ng = (t & 3) * 8;
      fl4 a, c;
#pragma unroll
      for (int j = 0; j < 4; ++j) {
        a[j] = tile[(ng + j) * 65 + d];
        c[j] = tile[(ng + 4 + j) * 65 + d];
      }
      *(f16x8*)(XT + ((size_t)b * 1024 + d0 + d) * 4096 + n0 + ng) = pk8(a, c);
    }
  } else if (id < 11264) {
    const int idx = id - 8192;
    const int z = idx >> 10;
    const float* in = (z == 0) ? Wq : (z == 1) ? Wk : Wv;
    __fp16* out = (z == 0) ? WqT : (z == 1) ? WkT : WvT;
    tr_cvt_body(tile, in, out, 1024, 1024, idx & 31, (idx >> 5) & 31);
  } else {
    const int idx = id - 11264;
    const int z = idx >> 10;
    tr_cvt_body(tile, z ? pv : pk, z ? pvT : pkT, 4096, 256, idx & 7,
                (idx >> 3) & 127);
  }
}

// ---------------------------------------------------------------------------
// Stage 1 (standalone, r17): Pk16[z][kk][dd] = sum_{n chunk c}
// pkT[kk][n]*XT[b][dd][n], z = c*4+b. 64kk x 64dd, BK=64, 16 iters.
// ---------------------------------------------------------------------------
__global__ __launch_bounds__(256) void stage1_partial(
    const __fp16* __restrict__ pkT,  // [256][4096]
    const __fp16* __restrict__ pvT,  // [256][4096]
    const __fp16* __restrict__ XT,   // [b][1024][4096]
    __fp16* __restrict__ Pk,         // [16][256][1024] f16 partials
    __fp16* __restrict__ Pv) {       // [16][256][1024]
  __shared__ __fp16 Ak[64 * 64];
  __shared__ __fp16 Av[64 * 64];
  __shared__ __fp16 Bx[64 * 64];
  const int t = threadIdx.x;
  const int lane = t & 63, w = t >> 6;
  const int lr = lane & 15, lg = lane >> 4;
  const int fid = blockIdx.x;
  const int g = fid >> 5, s5 = fid & 31;
  const int kk0 = (s5 >> 3) * 64, p8 = s5 & 7;
  const int pr = g * 8 + p8;
  const int dd0 = (pr & 15) * 64;
  const int z = pr >> 4, b = z & 3, c = z >> 2;
  const int wr = (w >> 1) * 32, wc = (w & 1) * 32;

  f32x4 acck[2][2], accv[2][2];
#pragma unroll
  for (int i = 0; i < 2; ++i)
#pragma unroll
    for (int j = 0; j < 2; ++j) {
      acck[i][j] = (f32x4){0.f, 0.f, 0.f, 0.f};
      accv[i][j] = (f32x4){0.f, 0.f, 0.f, 0.f};
    }

  const int r8 = lane >> 3, c8 = lane & 7;
  const int ssw = ((c8 ^ r8) * 8);
  const __fp16* pkS0 = pkT + (size_t)(kk0 + w * 8 + r8) * 4096 + c * 1024 + ssw;
  const __fp16* pkS1 = pkS0 + (size_t)32 * 4096;
  const __fp16* pvS0 = pvT + (size_t)(kk0 + w * 8 + r8) * 4096 + c * 1024 + ssw;
  const __fp16* pvS1 = pvS0 + (size_t)32 * 4096;
  const __fp16* xS0 =
      XT + ((size_t)b * 1024 + dd0 + w * 8 + r8) * 4096 + c * 1024 + ssw;
  const __fp16* xS1 = xS0 + (size_t)32 * 4096;

  for (int it = 0; it < 16; ++it) {
    const int n0 = it * 64;
    __syncthreads();
    gload_lds16(pkS0 + n0, (char*)Ak + w * 1024);
    gload_lds16(pkS1 + n0, (char*)Ak + 4096 + w * 1024);
    gload_lds16(pvS0 + n0, (char*)Av + w * 1024);
    gload_lds16(pvS1 + n0, (char*)Av + 4096 + w * 1024);
    gload_lds16(xS0 + n0, (char*)Bx + w * 1024);
    gload_lds16(xS1 + n0, (char*)Bx + 4096 + w * 1024);
    __syncthreads();

#pragma unroll
    for (int s = 0; s < 2; ++s) {
      f16x8 ak[2], av[2], bx[2];
#pragma unroll
      for (int i = 0; i < 2; ++i) {
        ak[i] = rd128(Ak, wr + i * 16 + lr, s * 4 + lg);
        av[i] = rd128(Av, wr + i * 16 + lr, s * 4 + lg);
      }
#pragma unroll
      for (int j = 0; j < 2; ++j)
        bx[j] = rd128(Bx, wc + j * 16 + lr, s * 4 + lg);
#pragma unroll
      for (int i = 0; i < 2; ++i)
#pragma unroll
        for (int j = 0; j < 2; ++j) {
          acck[i][j] = MFMA16(ak[i], bx[j], acck[i][j]);
          accv[i][j] = MFMA16(av[i], bx[j], accv[i][j]);
        }
    }
  }

#pragma unroll
  for (int i = 0; i < 2; ++i)
#pragma unroll
    for (int j = 0; j < 2; ++j)
#pragma unroll
      for (int r = 0; r < 4; ++r) {
        const size_t row = (size_t)z * 256 + kk0 + wr + i * 16 + lg * 4 + r;
        const int col = dd0 + wc + j * 16 + lr;
        Pk[row * 1024 + col] = (__fp16)acck[i][j][r];
        Pv[row * 1024 + col] = (__fp16)accv[i][j][r];
      }
}

// ---------------------------------------------------------------------------
// Q-path GEMM (standalone, r17): 256x128 tile, 8 waves, BK=64, 16 iters.
// ---------------------------------------------------------------------------
__global__ __launch_bounds__(512) void gemm_q(
    const __fp16* __restrict__ Xf,   // [16384][1024] f16
    const __fp16* __restrict__ WT,   // [1024][1024], WT[n][k] = W[k][n]
    __fp16* __restrict__ Q) {
  constexpr int K = 1024, N = 1024;
  __shared__ __fp16 Xs[256 * 64];  // 32KB
  __shared__ __fp16 Ws[128 * 64];  // 16KB
  const int t = threadIdx.x;
  const int lane = t & 63, w = t >> 6;        // w in [0,8)
  const int lr = lane & 15, lg = lane >> 4;
  const int fid = blockIdx.x;
  const int m0 = (fid & 63) * 256;
  const int n0 = (fid >> 6) * 128;
  const int wr = (w & 3) * 64, wc = (w >> 2) * 64;

  f32x4 acc[4][4];
#pragma unroll
  for (int i = 0; i < 4; ++i)
#pragma unroll
    for (int j = 0; j < 4; ++j) acc[i][j] = (f32x4){0.f, 0.f, 0.f, 0.f};

  const int r8 = lane >> 3, c8 = lane & 7;
  const int ssw = ((c8 ^ r8) * 8);
  const __fp16* xS = Xf + (size_t)(m0 + w * 8 + r8) * K + ssw;
  const __fp16* wS = WT + (size_t)(n0 + w * 8 + r8) * K + ssw;

  for (int it = 0; it < 16; ++it) {
    const int k0 = it * 64;
    __syncthreads();
#pragma unroll
    for (int i = 0; i < 4; ++i)
      gload_lds16(xS + (size_t)i * 64 * K + k0, (char*)Xs + i * 8192 + w * 1024);
#pragma unroll
    for (int i = 0; i < 2; ++i)
      gload_lds16(wS + (size_t)i * 64 * K + k0, (char*)Ws + i * 8192 + w * 1024);
    __syncthreads();

#pragma unroll
    for (int s = 0; s < 2; ++s) {
      f16x8 af[4], bf[4];
#pragma unroll
      for (int i = 0; i < 4; ++i)
        af[i] = rd128(Xs, wr + i * 16 + lr, s * 4 + lg);
#pragma unroll
      for (int j = 0; j < 4; ++j)
        bf[j] = rd128(Ws, wc + j * 16 + lr, s * 4 + lg);
#pragma unroll
      for (int i = 0; i < 4; ++i)
#pragma unroll
        for (int j = 0; j < 4; ++j)
          acc[i][j] = MFMA16(af[i], bf[j], acc[i][j]);
    }
  }

#pragma unroll
  for (int i = 0; i < 4; ++i)
#pragma unroll
    for (int j = 0; j < 4; ++j)
#pragma unroll
      for (int r = 0; r < 4; ++r) {
        const int row = m0 + wr + i * 16 + lg * 4 + r;
        const int col = n0 + wc + j * 16 + lr;
        Q[(size_t)row * N + col] = (__fp16)acc[i][j][r];
      }
}

// ---------------------------------------------------------------------------
// midphase: gemm_q (blocks 0..511, 512 thr) + stage1 (blocks 512..1535,
// 256 active thr, barriers uniform) in ONE launch. Requires partials to
// live OUTSIDE the Qh region (layout B only).
// ---------------------------------------------------------------------------
__global__ __launch_bounds__(512) void midphase(
    const __fp16* __restrict__ Xf, const __fp16* __restrict__ WqT,
    __fp16* __restrict__ Q,
    const __fp16* __restrict__ pkT, const __fp16* __restrict__ pvT,
    const __fp16* __restrict__ XT,
    __fp16* __restrict__ Pk, __fp16* __restrict__ Pv) {
  __shared__ __fp16 smem[24576];  // 48KB union
  const int id = blockIdx.x;
  const int t = threadIdx.x;
  const int lane = t & 63, w = t >> 6;
  const int lr = lane & 15, lg = lane >> 4;
  const int r8 = lane >> 3, c8 = lane & 7;
  const int ssw = ((c8 ^ r8) * 8);

  if (id < 512) {
    // ---- gemm_q body (verbatim r17) ----
    constexpr int K = 1024, N = 1024;
    __fp16* Xs = smem;          // 256*64
    __fp16* Ws = smem + 16384;  // 128*64
    const int m0 = (id & 63) * 256;
    const int n0 = (id >> 6) * 128;
    const int wr = (w & 3) * 64, wc = (w >> 2) * 64;

    f32x4 acc[4][4];
#pragma unroll
    for (int i = 0; i < 4; ++i)
#pragma unroll
      for (int j = 0; j < 4; ++j) acc[i][j] = (f32x4){0.f, 0.f, 0.f, 0.f};

    const __fp16* xS = Xf + (size_t)(m0 + w * 8 + r8) * K + ssw;
    const __fp16* wS = WqT + (size_t)(n0 + w * 8 + r8) * K + ssw;

    for (int it = 0; it < 16; ++it) {
      const int k0 = it * 64;
      __syncthreads();
#pragma unroll
      for (int i = 0; i < 4; ++i)
        gload_lds16(xS + (size_t)i * 64 * K + k0, (char*)Xs + i * 8192 + w * 1024);
#pragma unroll
      for (int i = 0; i < 2; ++i)
        gload_lds16(wS + (size_t)i * 64 * K + k0, (char*)Ws + i * 8192 + w * 1024);
      __syncthreads();

#pragma unroll
      for (int s = 0; s < 2; ++s) {
        f16x8 af[4], bf[4];
#pragma unroll
        for (int i = 0; i < 4; ++i)
          af[i] = rd128(Xs, wr + i * 16 + lr, s * 4 + lg);
#pragma unroll
        for (int j = 0; j < 4; ++j)
          bf[j] = rd128(Ws, wc + j * 16 + lr, s * 4 + lg);
#pragma unroll
        for (int i = 0; i < 4; ++i)
#pragma unroll
          for (int j = 0; j < 4; ++j)
            acc[i][j] = MFMA16(af[i], bf[j], acc[i][j]);
      }
    }

#pragma unroll
    for (int i = 0; i < 4; ++i)
#pragma unroll
      for (int j = 0; j < 4; ++j)
#pragma unroll
        for (int r = 0; r < 4; ++r) {
          const int row = m0 + wr + i * 16 + lg * 4 + r;
          const int col = n0 + wc + j * 16 + lr;
          Q[(size_t)row * N + col] = (__fp16)acc[i][j][r];
        }
  } else {
    // ---- stage1 body (r17) on waves 0..3; waves 4..7 barrier-only ----
    __fp16* Ak = smem;           // 64*64
    __fp16* Av = smem + 4096;
    __fp16* Bx = smem + 8192;
    const int fid = id - 512;
    const int g = fid >> 5, s5 = fid & 31;
    const int kk0 = (s5 >> 3) * 64, p8 = s5 & 7;
    const int pr = g * 8 + p8;
    const int dd0 = (pr & 15) * 64;
    const int z = pr >> 4, b = z & 3, c = z >> 2;
    const int wr = (w >> 1) * 32, wc = (w & 1) * 32;

    f32x4 acck[2][2], accv[2][2];
#pragma unroll
    for (int i = 0; i < 2; ++i)
#pragma unroll
      for (int j = 0; j < 2; ++j) {
        acck[i][j] = (f32x4){0.f, 0.f, 0.f, 0.f};
        accv[i][j] = (f32x4){0.f, 0.f, 0.f, 0.f};
      }

    const __fp16* pkS0 = pkT + (size_t)(kk0 + (w & 3) * 8 + r8) * 4096 + c * 1024 + ssw;
    const __fp16* pkS1 = pkS0 + (size_t)32 * 4096;
    const __fp16* pvS0 = pvT + (size_t)(kk0 + (w & 3) * 8 + r8) * 4096 + c * 1024 + ssw;
    const __fp16* pvS1 = pvS0 + (size_t)32 * 4096;
    const __fp16* xS0 =
        XT + ((size_t)b * 1024 + dd0 + (w & 3) * 8 + r8) * 4096 + c * 1024 + ssw;
    const __fp16* xS1 = xS0 + (size_t)32 * 4096;

    for (int it = 0; it < 16; ++it) {
      const int n0 = it * 64;
      __syncthreads();
      if (w < 4) {
        gload_lds16(pkS0 + n0, (char*)Ak + w * 1024);
        gload_lds16(pkS1 + n0, (char*)Ak + 4096 + w * 1024);
        gload_lds16(pvS0 + n0, (char*)Av + w * 1024);
        gload_lds16(pvS1 + n0, (char*)Av + 4096 + w * 1024);
        gload_lds16(xS0 + n0, (char*)Bx + w * 1024);
        gload_lds16(xS1 + n0, (char*)Bx + 4096 + w * 1024);
      }
      __syncthreads();

      if (w < 4) {
#pragma unroll
        for (int s = 0; s < 2; ++s) {
          f16x8 ak[2], av[2], bx[2];
#pragma unroll
          for (int i = 0; i < 2; ++i) {
            ak[i] = rd128(Ak, wr + i * 16 + lr, s * 4 + lg);
            av[i] = rd128(Av, wr + i * 16 + lr, s * 4 + lg);
          }
#pragma unroll
          for (int j = 0; j < 2; ++j)
            bx[j] = rd128(Bx, wc + j * 16 + lr, s * 4 + lg);
#pragma unroll
          for (int i = 0; i < 2; ++i)
#pragma unroll
            for (int j = 0; j < 2; ++j) {
              acck[i][j] = MFMA16(ak[i], bx[j], acck[i][j]);
              accv[i][j] = MFMA16(av[i], bx[j], accv[i][j]);
            }
        }
      }
    }

    if (w < 4) {
#pragma unroll
      for (int i = 0; i < 2; ++i)
#pragma unroll
        for (int j = 0; j < 2; ++j)
#pragma unroll
          for (int r = 0; r < 4; ++r) {
            const size_t row = (size_t)z * 256 + kk0 + wr + i * 16 + lg * 4 + r;
            const int col = dd0 + wc + j * 16 + lr;
            Pk[row * 1024 + col] = (__fp16)acck[i][j][r];
            Pv[row * 1024 + col] = (__fp16)accv[i][j][r];
          }
    }
  }
}

// ---------------------------------------------------------------------------
// Stage 1 reduce (f16 in, f32 accum): Xk = f16(sum_c Pk16[c*4+b]).
// ---------------------------------------------------------------------------
__global__ __launch_bounds__(256) void stage1_reduce(
    const __fp16* __restrict__ Pk, const __fp16* __restrict__ Pv,
    __fp16* __restrict__ Xk, __fp16* __restrict__ Xv) {
  const size_t idx = ((size_t)blockIdx.x * 256 + threadIdx.x) * 8;
  const int b = (int)(idx >> 18);           // 262144 elems per batch slab
  const size_t rem = idx & 0x3FFFFu;
  float sk[8], sv[8];
#pragma unroll
  for (int j = 0; j < 8; ++j) { sk[j] = 0.f; sv[j] = 0.f; }
#pragma unroll
  for (int c = 0; c < 4; ++c) {
    const size_t off = (((size_t)(c * 4 + b)) << 18) + rem;
    f16x8 vk = *(const f16x8*)(Pk + off);
    f16x8 vv = *(const f16x8*)(Pv + off);
#pragma unroll
    for (int j = 0; j < 8; ++j) {
      sk[j] += (float)vk[j];
      sv[j] += (float)vv[j];
    }
  }
  f16x8 ok, ov;
#pragma unroll
  for (int j = 0; j < 8; ++j) {
    ok[j] = (__fp16)sk[j];
    ov[j] = (__fp16)sv[j];
  }
  *(f16x8*)(Xk + idx) = ok;
  *(f16x8*)(Xv + idx) = ov;
}

// ---------------------------------------------------------------------------
// bt64z: both small BT-GEMMs in one launch (512 blocks).
// ---------------------------------------------------------------------------
__global__ __launch_bounds__(256) void bt64z(
    const __fp16* __restrict__ Xk, const __fp16* __restrict__ WkT,
    __fp16* __restrict__ Kp, const __fp16* __restrict__ WvT,
    const __fp16* __restrict__ Xv, __fp16* __restrict__ Vpt) {
  constexpr int E = 1024;
  __shared__ __fp16 As[64 * 64];
  __shared__ __fp16 Bs[64 * 64];
  const int t = threadIdx.x;
  const int lane = t & 63, w = t >> 6;
  const int lr = lane & 15, lg = lane >> 4;
  int id = blockIdx.x;
  const __fp16 *A, *B;
  __fp16* C;
  int i0, j0, ldC;
  if (id < 256) {
    const int x = id & 3, y = (id >> 2) & 15, z = id >> 6;
    A = Xk + (size_t)z * 256 * 1024; B = WkT;
    C = Kp + (size_t)z * 256 * 1024;
    i0 = x * 64; j0 = y * 64; ldC = 1024;
  } else {
    id -= 256;
    const int x = id & 15, y = (id >> 4) & 3, z = id >> 6;
    A = WvT; B = Xv + (size_t)z * 256 * 1024;
    C = Vpt + (size_t)z * 1024 * 256;
    i0 = x * 64; j0 = y * 64; ldC = 256;
  }
  const int wr = (w >> 1) * 32, wc = (w & 1) * 32;

  f32x4 acc[2][2];
#pragma unroll
  for (int i = 0; i < 2; ++i)
#pragma unroll
    for (int j = 0; j < 2; ++j) acc[i][j] = (f32x4){0.f, 0.f, 0.f, 0.f};

  const int r8 = lane >> 3, c8 = lane & 7;
  const int ssw = ((c8 ^ r8) * 8);
  const __fp16* aS0 = A + (size_t)(i0 + w * 8 + r8) * E + ssw;
  const __fp16* aS1 = aS0 + (size_t)32 * E;
  const __fp16* bS0 = B + (size_t)(j0 + w * 8 + r8) * E + ssw;
  const __fp16* bS1 = bS0 + (size_t)32 * E;

  for (int it = 0; it < 16; ++it) {
    const int e0 = it * 64;
    __syncthreads();
    gload_lds16(aS0 + e0, (char*)As + w * 1024);
    gload_lds16(aS1 + e0, (char*)As + 4096 + w * 1024);
    gload_lds16(bS0 + e0, (char*)Bs + w * 1024);
    gload_lds16(bS1 + e0, (char*)Bs + 4096 + w * 1024);
    __syncthreads();

#pragma unroll
    for (int s = 0; s < 2; ++s) {
      f16x8 af[2], bf[2];
#pragma unroll
      for (int i = 0; i < 2; ++i)
        af[i] = rd128(As, wr + i * 16 + lr, s * 4 + lg);
#pragma unroll
      for (int j = 0; j < 2; ++j)
        bf[j] = rd128(Bs, wc + j * 16 + lr, s * 4 + lg);
#pragma unroll
      for (int i = 0; i < 2; ++i)
#pragma unroll
        for (int j = 0; j < 2; ++j)
          acc[i][j] = MFMA16(af[i], bf[j], acc[i][j]);
    }
  }

#pragma unroll
  for (int i = 0; i < 2; ++i)
#pragma unroll
    for (int j = 0; j < 2; ++j)
#pragma unroll
      for (int r = 0; r < 4; ++r) {
        const int row = i0 + wr + i * 16 + lg * 4 + r;
        const int col = j0 + wc + j * 16 + lr;
        C[(size_t)row * ldC + col] = (__fp16)acc[i][j][r];
      }
}

// ---------------------------------------------------------------------------
// Attention v3 (verified r8-r17): block = 4 waves, 128 Q-rows of one (b,h);
// grid 2048. 32KB LDS (K then V), swapped QK^T, in-register P via
// cvt_pk + ds_bpermute.
// ---------------------------------------------------------------------------
__global__ __launch_bounds__(256) void attn_k(
    const __fp16* __restrict__ Q,    // [b*4096][1024]
    const __fp16* __restrict__ Kp,   // [b][256][1024]
    const __fp16* __restrict__ Vpt,  // [b][1024][256]
    float* __restrict__ O) {         // [b*4096][1024] f32
  __shared__ __fp16 KV[256 * 64];    // 32KB: K tile, then V^T tile
  const int t = threadIdx.x;
  const int lane = t & 63, w = t >> 6;
  const int lr = lane & 15, lg = lane >> 4;
  const int bh = blockIdx.x >> 5, rb = blockIdx.x & 31;
  const int b = bh >> 4, h = bh & 15;
  const int m0 = rb * 128 + w * 32;

  const __fp16* Kph = Kp + (size_t)b * 256 * 1024 + h * 64;
  const __fp16* Vph = Vpt + ((size_t)b * 1024 + h * 64) * 256;
  const __fp16* Qh = Q + ((size_t)(b * 4096 + m0)) * 1024 + h * 64;

#pragma unroll
  for (int i = 0; i < 8; ++i) {
    const int kr = (i * 4 + w) * 8 + (lane >> 3);
    gload_lds16(Kph + (size_t)kr * 1024 + (((lane & 7) ^ (kr & 7)) * 8),
                (char*)KV + (i * 4 + w) * 1024);
  }

  f16x8 aq[2][2];
#pragma unroll
  for (int mi = 0; mi < 2; ++mi)
#pragma unroll
    for (int s = 0; s < 2; ++s)
      aq[mi][s] =
          *(const f16x8*)(Qh + (size_t)(mi * 16 + lr) * 1024 + s * 32 + lg * 8);

  __syncthreads();  // K staged

  f32x4 dots[2][16];
#pragma unroll
  for (int mi = 0; mi < 2; ++mi)
#pragma unroll
    for (int jt = 0; jt < 16; ++jt) dots[mi][jt] = (f32x4){0.f, 0.f, 0.f, 0.f};
#pragma unroll
  for (int jt = 0; jt < 16; ++jt) {
    const int r = jt * 16 + lr;
    f16x8 k0 = *(const f16x8*)((const char*)KV + r * 128 + ((lg ^ (r & 7)) * 16));
    f16x8 k1 =
        *(const f16x8*)((const char*)KV + r * 128 + (((4 + lg) ^ (r & 7)) * 16));
    dots[0][jt] = MFMA16(k0, aq[0][0], dots[0][jt]);
    dots[0][jt] = MFMA16(k1, aq[0][1], dots[0][jt]);
    dots[1][jt] = MFMA16(k0, aq[1][0], dots[1][jt]);
    dots[1][jt] = MFMA16(k1, aq[1][1], dots[1][jt]);
  }

  unsigned cpk[2][16][2];
  float smv[2];
#pragma unroll
  for (int mi = 0; mi < 2; ++mi) {
    float mx = -1e30f;
#pragma unroll
    for (int jt = 0; jt < 16; ++jt)
#pragma unroll
      for (int r = 0; r < 4; ++r) mx = fmaxf(mx, dots[mi][jt][r]);
    mx = fmaxf(mx, __shfl_xor(mx, 16, 64));
    mx = fmaxf(mx, __shfl_xor(mx, 32, 64));
    float sm = 0.f;
#pragma unroll
    for (int jt = 0; jt < 16; ++jt) {
#pragma unroll
      for (int r = 0; r < 4; ++r) {
        float p = __expf(dots[mi][jt][r] - mx);
        dots[mi][jt][r] = p;
        sm += p;
      }
      cpk[mi][jt][0] = pk2u(dots[mi][jt][0], dots[mi][jt][1]);
      cpk[mi][jt][1] = pk2u(dots[mi][jt][2], dots[mi][jt][3]);
    }
    sm += __shfl_xor(sm, 16, 64);
    sm += __shfl_xor(sm, 32, 64);
    smv[mi] = sm;
  }

  __syncthreads();  // all waves done reading K

#pragma unroll
  for (int i = 0; i < 8; ++i) {
    const int dd = (i * 4 + w) * 2 + (lane >> 5);
    gload_lds16(Vph + (size_t)dd * 256 + (((lane & 31) ^ (dd & 7)) * 8),
                (char*)KV + (i * 4 + w) * 1024);
  }
  __syncthreads();  // V staged

#pragma unroll
  for (int mi = 0; mi < 2; ++mi) {
    f32x4 o[4];
#pragma unroll
    for (int j = 0; j < 4; ++j) o[j] = (f32x4){0.f, 0.f, 0.f, 0.f};
#pragma unroll
    for (int ks = 0; ks < 8; ++ks) {
      u32x4 wds;
#pragma unroll
      for (int m = 0; m < 4; ++m) {
        const int addr = ((((lane & 16) >> 3) + (m >> 1)) * 16 + lr) * 4;
        const int a0 = __builtin_amdgcn_ds_bpermute(
            addr, (int)cpk[mi][ks * 2][m & 1]);
        const int a1 = __builtin_amdgcn_ds_bpermute(
            addr, (int)cpk[mi][ks * 2 + 1][m & 1]);
        wds[m] = (unsigned)((lg >> 1) ? a1 : a0);
      }
      f16x8 pa = __builtin_bit_cast(f16x8, wds);
#pragma unroll
      for (int jt2 = 0; jt2 < 4; ++jt2) {
        const int dd = jt2 * 16 + lr;
        f16x8 bv = *(const f16x8*)((const char*)KV + dd * 512 +
                                   (((ks * 4 + lg) ^ (dd & 7)) * 16));
        o[jt2] = MFMA16(pa, bv, o[jt2]);
      }
    }

    float rs[4];
#pragma unroll
    for (int r = 0; r < 4; ++r)
      rs[r] = 1.f / __shfl(smv[mi], (lane & 48) + lg * 4 + r, 64);
#pragma unroll
    for (int jt2 = 0; jt2 < 4; ++jt2)
#pragma unroll
      for (int r = 0; r < 4; ++r) {
        const size_t row = (size_t)(b * 4096 + m0 + mi * 16 + lg * 4 + r);
        O[row * 1024 + h * 64 + jt2 * 16 + lr] = o[jt2][r] * rs[r];
      }
  }
}

// ---------------------------------------------------------------------------
extern "C" void kernel_launch(void* const* d_in, const int* in_sizes, int n_in,
                              void* d_out, int out_size, void* d_ws, size_t ws_size,
                              hipStream_t stream) {
  (void)in_sizes; (void)n_in; (void)out_size;
  const float* x  = (const float*)d_in[0];
  const float* Wq = (const float*)d_in[1];
  const float* Wk = (const float*)d_in[2];
  const float* Wv = (const float*)d_in[3];
  const float* pk = (const float*)d_in[4];
  const float* pv = (const float*)d_in[5];
  float* out = (float*)d_out;

  // ws base layout (f16), 50 MiB:
  __fp16* Qh  = (__fp16*)d_ws;                       // 16384*1024 f16 (32MB)
  __fp16* WqT = Qh  + (size_t)16384 * 1024;          // 1024*1024 each
  __fp16* WkT = WqT + (size_t)1024 * 1024;
  __fp16* WvT = WkT + (size_t)1024 * 1024;
  __fp16* pkT = WvT + (size_t)1024 * 1024;           // 256*4096 each
  __fp16* pvT = pkT + (size_t)256 * 4096;
  __fp16* Xk  = pvT + (size_t)256 * 4096;            // 4*256*1024 each
  __fp16* Xv  = Xk  + (size_t)4 * 256 * 1024;
  __fp16* Kp  = Xv  + (size_t)4 * 256 * 1024;
  __fp16* Vpt = Kp  + (size_t)4 * 256 * 1024;
  __fp16* wsEnd = Vpt + (size_t)4 * 256 * 1024;      // = d_ws + 52,428,800 B
  // d_out scratch: Xf16 + XT (fully overwritten by attn_k at the end)
  __fp16* Xf16 = (__fp16*)d_out;                     // 4*4096*1024 f16
  __fp16* XT   = Xf16 + (size_t)4 * 4096 * 1024;     // 4*1024*4096 f16

  // Partials: layout B (own region after Vpt) if ws is big enough -> merged
  // midphase; else layout A (alias Qh region) -> serial (r17 flow).
  const size_t needB = 52428800ULL + 2ULL * 16 * 256 * 1024 * 2;  // +16MB
  const bool bigWs = (ws_size >= needB);
  __fp16* Pk16 = bigWs ? wsEnd : (__fp16*)d_ws;
  __fp16* Pv16 = Pk16 + (size_t)16 * 256 * 1024;

  const dim3 bb(256);

  // 0. all conversions in one launch
  prep<<<dim3(13312), bb, 0, stream>>>(x, Xf16, XT, Wq, Wk, Wv, WqT, WkT, WvT,
                                       pk, pv, pkT, pvT);

  if (bigWs) {
    // 1+3 merged: gemm_q + stage1 (independent; partials not in Qh region)
    midphase<<<dim3(1536), dim3(512), 0, stream>>>(Xf16, WqT, Qh, pkT, pvT, XT,
                                                   Pk16, Pv16);
    stage1_reduce<<<dim3(512), bb, 0, stream>>>(Pk16, Pv16, Xk, Xv);
    bt64z<<<dim3(512), bb, 0, stream>>>(Xk, WkT, Kp, WvT, Xv, Vpt);
  } else {
    // serial fallback (exact r17 flow)
    stage1_partial<<<dim3(1024), bb, 0, stream>>>(pkT, pvT, XT, Pk16, Pv16);
    stage1_reduce<<<dim3(512), bb, 0, stream>>>(Pk16, Pv16, Xk, Xv);
    bt64z<<<dim3(512), bb, 0, stream>>>(Xk, WkT, Kp, WvT, Xv, Vpt);
    gemm_q<<<dim3(512), dim3(512), 0, stream>>>(Xf16, WqT, Qh);
  }

  // 4. attention (overwrites Xf16/XT = d_out)
  attn_k<<<dim3(2048), bb, 0, stream>>>(Qh, Kp, Vpt, out);
}

// Round 19
// 151.744 us; speedup vs baseline: 1.0388x; 1.0388x over previous
//
#include <hip/hip_runtime.h>

// ---------------------------------------------------------------------------
// Linformer self-attention, fp32 I/O, fp16 MFMA internally, MI355X (gfx950)
// b=4 n=4096 d=1024 h=16 dh=64 k=256  (no 1/sqrt(dh) scale per reference)
//
// Round 19: midphase v2 — gemm_q (blocks 0..511) + stage1 packed TWO tiles
// per block (blocks 512..1023, wave-group g = w>>2 owns tile 2*(id-512)+g in
// its own 24KB LDS half). All threads active, LDS fully used. Serial r17
// fallback when ws is small. All tile bodies verified unchanged.
// ---------------------------------------------------------------------------

typedef __fp16 f16x8 __attribute__((ext_vector_type(8)));
typedef __fp16 f16x2 __attribute__((ext_vector_type(2)));
typedef float fl4 __attribute__((ext_vector_type(4)));
typedef float f32x4 __attribute__((ext_vector_type(4)));
typedef unsigned int u32x2 __attribute__((ext_vector_type(2)));
typedef unsigned int u32x4 __attribute__((ext_vector_type(4)));

#define MFMA16(a, b, c) __builtin_amdgcn_mfma_f32_16x16x32_f16((a), (b), (c), 0, 0, 0)

__device__ __forceinline__ unsigned int pk2u(float a, float b) {
  f16x2 p = __builtin_amdgcn_cvt_pkrtz(a, b);  // low = a, high = b
  return __builtin_bit_cast(unsigned int, p);
}

__device__ __forceinline__ f16x8 pk8(fl4 a, fl4 b) {
  f16x2 p0 = __builtin_amdgcn_cvt_pkrtz(a[0], a[1]);
  f16x2 p1 = __builtin_amdgcn_cvt_pkrtz(a[2], a[3]);
  f16x2 p2 = __builtin_amdgcn_cvt_pkrtz(b[0], b[1]);
  f16x2 p3 = __builtin_amdgcn_cvt_pkrtz(b[2], b[3]);
  f16x8 r;
  r[0] = p0[0]; r[1] = p0[1]; r[2] = p1[0]; r[3] = p1[1];
  r[4] = p2[0]; r[5] = p2[1]; r[6] = p3[0]; r[7] = p3[1];
  return r;
}

__device__ __forceinline__ void gload_lds16(const __fp16* g, void* lds_base) {
  __builtin_amdgcn_global_load_lds(
      (const __attribute__((address_space(1))) void*)g,
      (__attribute__((address_space(3))) void*)lds_base, 16, 0, 0);
}

// 128B-row tile fragment read: logical 16B chunk `ch` of `row`
__device__ __forceinline__ f16x8 rd128(const __fp16* base, int row, int ch) {
  return *(const f16x8*)((const char*)base + row * 128 +
                         ((ch ^ (row & 7)) * 16));
}

// ---------------------------------------------------------------------------
// prep: one launch. Blocks [0,8192): xprep (X f32 -> Xf16 + XT f16).
// [8192,11264): 3x W 1024x1024 transpose+cvt. [11264,13312): 2x proj
// 4096x256 transpose+cvt.
// ---------------------------------------------------------------------------
__device__ __forceinline__ void tr_cvt_body(
    float* tile, const float* in, __fp16* out, int R, int C, int bx, int by) {
  const int t = threadIdx.x;
  const int c0 = bx * 32, r0 = by * 32;
  {
    const int r = t >> 3, cg = (t & 7) * 4;
    fl4 v = *(const fl4*)(in + (size_t)(r0 + r) * C + c0 + cg);
    tile[r * 33 + cg] = v[0]; tile[r * 33 + cg + 1] = v[1];
    tile[r * 33 + cg + 2] = v[2]; tile[r * 33 + cg + 3] = v[3];
  }
  __syncthreads();
  {
    const int cc = t >> 3, rg = (t & 7) * 4;
    u32x2 p;
    p[0] = pk2u(tile[(rg + 0) * 33 + cc], tile[(rg + 1) * 33 + cc]);
    p[1] = pk2u(tile[(rg + 2) * 33 + cc], tile[(rg + 3) * 33 + cc]);
    *(u32x2*)(out + (size_t)(c0 + cc) * R + r0 + rg) = p;
  }
}

__global__ __launch_bounds__(256) void prep(
    const float* __restrict__ X, __fp16* __restrict__ Xf,
    __fp16* __restrict__ XT,
    const float* __restrict__ Wq, const float* __restrict__ Wk,
    const float* __restrict__ Wv, __fp16* __restrict__ WqT,
    __fp16* __restrict__ WkT, __fp16* __restrict__ WvT,
    const float* __restrict__ pk, const float* __restrict__ pv,
    __fp16* __restrict__ pkT, __fp16* __restrict__ pvT) {
  __shared__ float tile[32 * 65];
  const int id = blockIdx.x;
  const int t = threadIdx.x;
  if (id < 8192) {
    // xprep: 32n x 64d tile
    const int n0 = (id & 127) * 32, d0 = ((id >> 7) & 15) * 64, b = id >> 11;
    const float* src = X + ((size_t)b * 4096 + n0) * 1024 + d0;
    {
      const int r = t >> 3, cg = (t & 7) * 8;
      fl4 v0 = *(const fl4*)(src + (size_t)r * 1024 + cg);
      fl4 v1 = *(const fl4*)(src + (size_t)r * 1024 + cg + 4);
      *(f16x8*)(Xf + ((size_t)b * 4096 + n0 + r) * 1024 + d0 + cg) = pk8(v0, v1);
#pragma unroll
      for (int j = 0; j < 4; ++j) {
        tile[r * 65 + cg + j] = v0[j];
        tile[r * 65 + cg + 4 + j] = v1[j];
      }
    }
    __syncthreads();
    {
      const int d = t >> 2, ng = (t & 3) * 8;
      fl4 a, c;
#pragma unroll
      for (int j = 0; j < 4; ++j) {
        a[j] = tile[(ng + j) * 65 + d];
        c[j] = tile[(ng + 4 + j) * 65 + d];
      }
      *(f16x8*)(XT + ((size_t)b * 1024 + d0 + d) * 4096 + n0 + ng) = pk8(a, c);
    }
  } else if (id < 11264) {
    const int idx = id - 8192;
    const int z = idx >> 10;
    const float* in = (z == 0) ? Wq : (z == 1) ? Wk : Wv;
    __fp16* out = (z == 0) ? WqT : (z == 1) ? WkT : WvT;
    tr_cvt_body(tile, in, out, 1024, 1024, idx & 31, (idx >> 5) & 31);
  } else {
    const int idx = id - 11264;
    const int z = idx >> 10;
    tr_cvt_body(tile, z ? pv : pk, z ? pvT : pkT, 4096, 256, idx & 7,
                (idx >> 3) & 127);
  }
}

// ---------------------------------------------------------------------------
// Stage 1 tile body (verified): one 64kk x 64dd tile of fid, executed by
// 4 waves (local wave ww in [0,4)) using the 24KB LDS at Ak/Av/Bx.
// ---------------------------------------------------------------------------
__device__ __forceinline__ void stage1_tile(
    const __fp16* __restrict__ pkT, const __fp16* __restrict__ pvT,
    const __fp16* __restrict__ XT, __fp16* __restrict__ Pk,
    __fp16* __restrict__ Pv, __fp16* Ak, __fp16* Av, __fp16* Bx,
    int fid, int ww, int lane) {
  const int lr = lane & 15, lg = lane >> 4;
  const int g = fid >> 5, s5 = fid & 31;
  const int kk0 = (s5 >> 3) * 64, p8 = s5 & 7;
  const int pr = g * 8 + p8;
  const int dd0 = (pr & 15) * 64;
  const int z = pr >> 4, b = z & 3, c = z >> 2;
  const int wr = (ww >> 1) * 32, wc = (ww & 1) * 32;

  f32x4 acck[2][2], accv[2][2];
#pragma unroll
  for (int i = 0; i < 2; ++i)
#pragma unroll
    for (int j = 0; j < 2; ++j) {
      acck[i][j] = (f32x4){0.f, 0.f, 0.f, 0.f};
      accv[i][j] = (f32x4){0.f, 0.f, 0.f, 0.f};
    }

  const int r8 = lane >> 3, c8 = lane & 7;
  const int ssw = ((c8 ^ r8) * 8);
  const __fp16* pkS0 = pkT + (size_t)(kk0 + ww * 8 + r8) * 4096 + c * 1024 + ssw;
  const __fp16* pkS1 = pkS0 + (size_t)32 * 4096;
  const __fp16* pvS0 = pvT + (size_t)(kk0 + ww * 8 + r8) * 4096 + c * 1024 + ssw;
  const __fp16* pvS1 = pvS0 + (size_t)32 * 4096;
  const __fp16* xS0 =
      XT + ((size_t)b * 1024 + dd0 + ww * 8 + r8) * 4096 + c * 1024 + ssw;
  const __fp16* xS1 = xS0 + (size_t)32 * 4096;

  for (int it = 0; it < 16; ++it) {
    const int n0 = it * 64;
    __syncthreads();
    gload_lds16(pkS0 + n0, (char*)Ak + ww * 1024);
    gload_lds16(pkS1 + n0, (char*)Ak + 4096 + ww * 1024);
    gload_lds16(pvS0 + n0, (char*)Av + ww * 1024);
    gload_lds16(pvS1 + n0, (char*)Av + 4096 + ww * 1024);
    gload_lds16(xS0 + n0, (char*)Bx + ww * 1024);
    gload_lds16(xS1 + n0, (char*)Bx + 4096 + ww * 1024);
    __syncthreads();

#pragma unroll
    for (int s = 0; s < 2; ++s) {
      f16x8 ak[2], av[2], bx[2];
#pragma unroll
      for (int i = 0; i < 2; ++i) {
        ak[i] = rd128(Ak, wr + i * 16 + lr, s * 4 + lg);
        av[i] = rd128(Av, wr + i * 16 + lr, s * 4 + lg);
      }
#pragma unroll
      for (int j = 0; j < 2; ++j)
        bx[j] = rd128(Bx, wc + j * 16 + lr, s * 4 + lg);
#pragma unroll
      for (int i = 0; i < 2; ++i)
#pragma unroll
        for (int j = 0; j < 2; ++j) {
          acck[i][j] = MFMA16(ak[i], bx[j], acck[i][j]);
          accv[i][j] = MFMA16(av[i], bx[j], accv[i][j]);
        }
    }
  }

#pragma unroll
  for (int i = 0; i < 2; ++i)
#pragma unroll
    for (int j = 0; j < 2; ++j)
#pragma unroll
      for (int r = 0; r < 4; ++r) {
        const size_t row = (size_t)z * 256 + kk0 + wr + i * 16 + lg * 4 + r;
        const int col = dd0 + wc + j * 16 + lr;
        Pk[row * 1024 + col] = (__fp16)acck[i][j][r];
        Pv[row * 1024 + col] = (__fp16)accv[i][j][r];
      }
}

// ---------------------------------------------------------------------------
// Stage 1 standalone (serial fallback): 1024 blocks, 4 waves each.
// ---------------------------------------------------------------------------
__global__ __launch_bounds__(256) void stage1_partial(
    const __fp16* __restrict__ pkT, const __fp16* __restrict__ pvT,
    const __fp16* __restrict__ XT, __fp16* __restrict__ Pk,
    __fp16* __restrict__ Pv) {
  __shared__ __fp16 smem[12288];  // Ak/Av/Bx = 3 x 4096
  const int t = threadIdx.x;
  stage1_tile(pkT, pvT, XT, Pk, Pv, smem, smem + 4096, smem + 8192,
              blockIdx.x, t >> 6, t & 63);
}

// ---------------------------------------------------------------------------
// gemm_q tile body (verified r17): 256x128, 8 waves, BK=64, 16 iters.
// ---------------------------------------------------------------------------
__device__ __forceinline__ void gemmq_tile(
    const __fp16* __restrict__ Xf, const __fp16* __restrict__ WT,
    __fp16* __restrict__ Q, __fp16* Xs, __fp16* Ws, int fid, int w,
    int lane) {
  constexpr int K = 1024, N = 1024;
  const int lr = lane & 15, lg = lane >> 4;
  const int m0 = (fid & 63) * 256;
  const int n0 = (fid >> 6) * 128;
  const int wr = (w & 3) * 64, wc = (w >> 2) * 64;

  f32x4 acc[4][4];
#pragma unroll
  for (int i = 0; i < 4; ++i)
#pragma unroll
    for (int j = 0; j < 4; ++j) acc[i][j] = (f32x4){0.f, 0.f, 0.f, 0.f};

  const int r8 = lane >> 3, c8 = lane & 7;
  const int ssw = ((c8 ^ r8) * 8);
  const __fp16* xS = Xf + (size_t)(m0 + w * 8 + r8) * K + ssw;
  const __fp16* wS = WT + (size_t)(n0 + w * 8 + r8) * K + ssw;

  for (int it = 0; it < 16; ++it) {
    const int k0 = it * 64;
    __syncthreads();
#pragma unroll
    for (int i = 0; i < 4; ++i)
      gload_lds16(xS + (size_t)i * 64 * K + k0, (char*)Xs + i * 8192 + w * 1024);
#pragma unroll
    for (int i = 0; i < 2; ++i)
      gload_lds16(wS + (size_t)i * 64 * K + k0, (char*)Ws + i * 8192 + w * 1024);
    __syncthreads();

#pragma unroll
    for (int s = 0; s < 2; ++s) {
      f16x8 af[4], bf[4];
#pragma unroll
      for (int i = 0; i < 4; ++i)
        af[i] = rd128(Xs, wr + i * 16 + lr, s * 4 + lg);
#pragma unroll
      for (int j = 0; j < 4; ++j)
        bf[j] = rd128(Ws, wc + j * 16 + lr, s * 4 + lg);
#pragma unroll
      for (int i = 0; i < 4; ++i)
#pragma unroll
        for (int j = 0; j < 4; ++j)
          acc[i][j] = MFMA16(af[i], bf[j], acc[i][j]);
    }
  }

#pragma unroll
  for (int i = 0; i < 4; ++i)
#pragma unroll
    for (int j = 0; j < 4; ++j)
#pragma unroll
      for (int r = 0; r < 4; ++r) {
        const int row = m0 + wr + i * 16 + lg * 4 + r;
        const int col = n0 + wc + j * 16 + lr;
        Q[(size_t)row * N + col] = (__fp16)acc[i][j][r];
      }
}

// ---------------------------------------------------------------------------
// gemm_q standalone (serial fallback).
// ---------------------------------------------------------------------------
__global__ __launch_bounds__(512) void gemm_q(
    const __fp16* __restrict__ Xf, const __fp16* __restrict__ WT,
    __fp16* __restrict__ Q) {
  __shared__ __fp16 smem[24576];  // Xs 16384 + Ws 8192
  const int t = threadIdx.x;
  gemmq_tile(Xf, WT, Q, smem, smem + 16384, blockIdx.x, t >> 6, t & 63);
}

// ---------------------------------------------------------------------------
// midphase v2: blocks 0..511 = gemm_q tile; blocks 512..1023 = TWO stage1
// tiles (wave-group g = w>>2 owns tile 2*(id-512)+g in 24KB LDS half).
// Barrier counts uniform across arms and groups.
// ---------------------------------------------------------------------------
__global__ __launch_bounds__(512) void midphase(
    const __fp16* __restrict__ Xf, const __fp16* __restrict__ WqT,
    __fp16* __restrict__ Q,
    const __fp16* __restrict__ pkT, const __fp16* __restrict__ pvT,
    const __fp16* __restrict__ XT,
    __fp16* __restrict__ Pk, __fp16* __restrict__ Pv) {
  __shared__ __fp16 smem[24576];  // 48KB union
  const int id = blockIdx.x;
  const int t = threadIdx.x;
  const int lane = t & 63, w = t >> 6;

  if (id < 512) {
    gemmq_tile(Xf, WqT, Q, smem, smem + 16384, id, w, lane);
  } else {
    const int grp = w >> 2, ww = w & 3;
    __fp16* base = smem + grp * 12288;
    stage1_tile(pkT, pvT, XT, Pk, Pv, base, base + 4096, base + 8192,
                (id - 512) * 2 + grp, ww, lane);
  }
}

// ---------------------------------------------------------------------------
// Stage 1 reduce (f16 in, f32 accum): Xk = f16(sum_c Pk16[c*4+b]).
// ---------------------------------------------------------------------------
__global__ __launch_bounds__(256) void stage1_reduce(
    const __fp16* __restrict__ Pk, const __fp16* __restrict__ Pv,
    __fp16* __restrict__ Xk, __fp16* __restrict__ Xv) {
  const size_t idx = ((size_t)blockIdx.x * 256 + threadIdx.x) * 8;
  const int b = (int)(idx >> 18);           // 262144 elems per batch slab
  const size_t rem = idx & 0x3FFFFu;
  float sk[8], sv[8];
#pragma unroll
  for (int j = 0; j < 8; ++j) { sk[j] = 0.f; sv[j] = 0.f; }
#pragma unroll
  for (int c = 0; c < 4; ++c) {
    const size_t off = (((size_t)(c * 4 + b)) << 18) + rem;
    f16x8 vk = *(const f16x8*)(Pk + off);
    f16x8 vv = *(const f16x8*)(Pv + off);
#pragma unroll
    for (int j = 0; j < 8; ++j) {
      sk[j] += (float)vk[j];
      sv[j] += (float)vv[j];
    }
  }
  f16x8 ok, ov;
#pragma unroll
  for (int j = 0; j < 8; ++j) {
    ok[j] = (__fp16)sk[j];
    ov[j] = (__fp16)sv[j];
  }
  *(f16x8*)(Xk + idx) = ok;
  *(f16x8*)(Xv + idx) = ov;
}

// ---------------------------------------------------------------------------
// bt64z: both small BT-GEMMs in one launch (512 blocks).
// ---------------------------------------------------------------------------
__global__ __launch_bounds__(256) void bt64z(
    const __fp16* __restrict__ Xk, const __fp16* __restrict__ WkT,
    __fp16* __restrict__ Kp, const __fp16* __restrict__ WvT,
    const __fp16* __restrict__ Xv, __fp16* __restrict__ Vpt) {
  constexpr int E = 1024;
  __shared__ __fp16 As[64 * 64];
  __shared__ __fp16 Bs[64 * 64];
  const int t = threadIdx.x;
  const int lane = t & 63, w = t >> 6;
  const int lr = lane & 15, lg = lane >> 4;
  int id = blockIdx.x;
  const __fp16 *A, *B;
  __fp16* C;
  int i0, j0, ldC;
  if (id < 256) {
    const int x = id & 3, y = (id >> 2) & 15, z = id >> 6;
    A = Xk + (size_t)z * 256 * 1024; B = WkT;
    C = Kp + (size_t)z * 256 * 1024;
    i0 = x * 64; j0 = y * 64; ldC = 1024;
  } else {
    id -= 256;
    const int x = id & 15, y = (id >> 4) & 3, z = id >> 6;
    A = WvT; B = Xv + (size_t)z * 256 * 1024;
    C = Vpt + (size_t)z * 1024 * 256;
    i0 = x * 64; j0 = y * 64; ldC = 256;
  }
  const int wr = (w >> 1) * 32, wc = (w & 1) * 32;

  f32x4 acc[2][2];
#pragma unroll
  for (int i = 0; i < 2; ++i)
#pragma unroll
    for (int j = 0; j < 2; ++j) acc[i][j] = (f32x4){0.f, 0.f, 0.f, 0.f};

  const int r8 = lane >> 3, c8 = lane & 7;
  const int ssw = ((c8 ^ r8) * 8);
  const __fp16* aS0 = A + (size_t)(i0 + w * 8 + r8) * E + ssw;
  const __fp16* aS1 = aS0 + (size_t)32 * E;
  const __fp16* bS0 = B + (size_t)(j0 + w * 8 + r8) * E + ssw;
  const __fp16* bS1 = bS0 + (size_t)32 * E;

  for (int it = 0; it < 16; ++it) {
    const int e0 = it * 64;
    __syncthreads();
    gload_lds16(aS0 + e0, (char*)As + w * 1024);
    gload_lds16(aS1 + e0, (char*)As + 4096 + w * 1024);
    gload_lds16(bS0 + e0, (char*)Bs + w * 1024);
    gload_lds16(bS1 + e0, (char*)Bs + 4096 + w * 1024);
    __syncthreads();

#pragma unroll
    for (int s = 0; s < 2; ++s) {
      f16x8 af[2], bf[2];
#pragma unroll
      for (int i = 0; i < 2; ++i)
        af[i] = rd128(As, wr + i * 16 + lr, s * 4 + lg);
#pragma unroll
      for (int j = 0; j < 2; ++j)
        bf[j] = rd128(Bs, wc + j * 16 + lr, s * 4 + lg);
#pragma unroll
      for (int i = 0; i < 2; ++i)
#pragma unroll
        for (int j = 0; j < 2; ++j)
          acc[i][j] = MFMA16(af[i], bf[j], acc[i][j]);
    }
  }

#pragma unroll
  for (int i = 0; i < 2; ++i)
#pragma unroll
    for (int j = 0; j < 2; ++j)
#pragma unroll
      for (int r = 0; r < 4; ++r) {
        const int row = i0 + wr + i * 16 + lg * 4 + r;
        const int col = j0 + wc + j * 16 + lr;
        C[(size_t)row * ldC + col] = (__fp16)acc[i][j][r];
      }
}

// ---------------------------------------------------------------------------
// Attention v3 (verified r8-r18): block = 4 waves, 128 Q-rows of one (b,h);
// grid 2048. 32KB LDS (K then V), swapped QK^T, in-register P via
// cvt_pk + ds_bpermute.
// ---------------------------------------------------------------------------
__global__ __launch_bounds__(256) void attn_k(
    const __fp16* __restrict__ Q,    // [b*4096][1024]
    const __fp16* __restrict__ Kp,   // [b][256][1024]
    const __fp16* __restrict__ Vpt,  // [b][1024][256]
    float* __restrict__ O) {         // [b*4096][1024] f32
  __shared__ __fp16 KV[256 * 64];    // 32KB: K tile, then V^T tile
  const int t = threadIdx.x;
  const int lane = t & 63, w = t >> 6;
  const int lr = lane & 15, lg = lane >> 4;
  const int bh = blockIdx.x >> 5, rb = blockIdx.x & 31;
  const int b = bh >> 4, h = bh & 15;
  const int m0 = rb * 128 + w * 32;

  const __fp16* Kph = Kp + (size_t)b * 256 * 1024 + h * 64;
  const __fp16* Vph = Vpt + ((size_t)b * 1024 + h * 64) * 256;
  const __fp16* Qh = Q + ((size_t)(b * 4096 + m0)) * 1024 + h * 64;

#pragma unroll
  for (int i = 0; i < 8; ++i) {
    const int kr = (i * 4 + w) * 8 + (lane >> 3);
    gload_lds16(Kph + (size_t)kr * 1024 + (((lane & 7) ^ (kr & 7)) * 8),
                (char*)KV + (i * 4 + w) * 1024);
  }

  f16x8 aq[2][2];
#pragma unroll
  for (int mi = 0; mi < 2; ++mi)
#pragma unroll
    for (int s = 0; s < 2; ++s)
      aq[mi][s] =
          *(const f16x8*)(Qh + (size_t)(mi * 16 + lr) * 1024 + s * 32 + lg * 8);

  __syncthreads();  // K staged

  f32x4 dots[2][16];
#pragma unroll
  for (int mi = 0; mi < 2; ++mi)
#pragma unroll
    for (int jt = 0; jt < 16; ++jt) dots[mi][jt] = (f32x4){0.f, 0.f, 0.f, 0.f};
#pragma unroll
  for (int jt = 0; jt < 16; ++jt) {
    const int r = jt * 16 + lr;
    f16x8 k0 = *(const f16x8*)((const char*)KV + r * 128 + ((lg ^ (r & 7)) * 16));
    f16x8 k1 =
        *(const f16x8*)((const char*)KV + r * 128 + (((4 + lg) ^ (r & 7)) * 16));
    dots[0][jt] = MFMA16(k0, aq[0][0], dots[0][jt]);
    dots[0][jt] = MFMA16(k1, aq[0][1], dots[0][jt]);
    dots[1][jt] = MFMA16(k0, aq[1][0], dots[1][jt]);
    dots[1][jt] = MFMA16(k1, aq[1][1], dots[1][jt]);
  }

  unsigned cpk[2][16][2];
  float smv[2];
#pragma unroll
  for (int mi = 0; mi < 2; ++mi) {
    float mx = -1e30f;
#pragma unroll
    for (int jt = 0; jt < 16; ++jt)
#pragma unroll
      for (int r = 0; r < 4; ++r) mx = fmaxf(mx, dots[mi][jt][r]);
    mx = fmaxf(mx, __shfl_xor(mx, 16, 64));
    mx = fmaxf(mx, __shfl_xor(mx, 32, 64));
    float sm = 0.f;
#pragma unroll
    for (int jt = 0; jt < 16; ++jt) {
#pragma unroll
      for (int r = 0; r < 4; ++r) {
        float p = __expf(dots[mi][jt][r] - mx);
        dots[mi][jt][r] = p;
        sm += p;
      }
      cpk[mi][jt][0] = pk2u(dots[mi][jt][0], dots[mi][jt][1]);
      cpk[mi][jt][1] = pk2u(dots[mi][jt][2], dots[mi][jt][3]);
    }
    sm += __shfl_xor(sm, 16, 64);
    sm += __shfl_xor(sm, 32, 64);
    smv[mi] = sm;
  }

  __syncthreads();  // all waves done reading K

#pragma unroll
  for (int i = 0; i < 8; ++i) {
    const int dd = (i * 4 + w) * 2 + (lane >> 5);
    gload_lds16(Vph + (size_t)dd * 256 + (((lane & 31) ^ (dd & 7)) * 8),
                (char*)KV + (i * 4 + w) * 1024);
  }
  __syncthreads();  // V staged

#pragma unroll
  for (int mi = 0; mi < 2; ++mi) {
    f32x4 o[4];
#pragma unroll
    for (int j = 0; j < 4; ++j) o[j] = (f32x4){0.f, 0.f, 0.f, 0.f};
#pragma unroll
    for (int ks = 0; ks < 8; ++ks) {
      u32x4 wds;
#pragma unroll
      for (int m = 0; m < 4; ++m) {
        const int addr = ((((lane & 16) >> 3) + (m >> 1)) * 16 + lr) * 4;
        const int a0 = __builtin_amdgcn_ds_bpermute(
            addr, (int)cpk[mi][ks * 2][m & 1]);
        const int a1 = __builtin_amdgcn_ds_bpermute(
            addr, (int)cpk[mi][ks * 2 + 1][m & 1]);
        wds[m] = (unsigned)((lg >> 1) ? a1 : a0);
      }
      f16x8 pa = __builtin_bit_cast(f16x8, wds);
#pragma unroll
      for (int jt2 = 0; jt2 < 4; ++jt2) {
        const int dd = jt2 * 16 + lr;
        f16x8 bv = *(const f16x8*)((const char*)KV + dd * 512 +
                                   (((ks * 4 + lg) ^ (dd & 7)) * 16));
        o[jt2] = MFMA16(pa, bv, o[jt2]);
      }
    }

    float rs[4];
#pragma unroll
    for (int r = 0; r < 4; ++r)
      rs[r] = 1.f / __shfl(smv[mi], (lane & 48) + lg * 4 + r, 64);
#pragma unroll
    for (int jt2 = 0; jt2 < 4; ++jt2)
#pragma unroll
      for (int r = 0; r < 4; ++r) {
        const size_t row = (size_t)(b * 4096 + m0 + mi * 16 + lg * 4 + r);
        O[row * 1024 + h * 64 + jt2 * 16 + lr] = o[jt2][r] * rs[r];
      }
  }
}

// ---------------------------------------------------------------------------
extern "C" void kernel_launch(void* const* d_in, const int* in_sizes, int n_in,
                              void* d_out, int out_size, void* d_ws, size_t ws_size,
                              hipStream_t stream) {
  (void)in_sizes; (void)n_in; (void)out_size;
  const float* x  = (const float*)d_in[0];
  const float* Wq = (const float*)d_in[1];
  const float* Wk = (const float*)d_in[2];
  const float* Wv = (const float*)d_in[3];
  const float* pk = (const float*)d_in[4];
  const float* pv = (const float*)d_in[5];
  float* out = (float*)d_out;

  // ws base layout (f16), 50 MiB:
  __fp16* Qh  = (__fp16*)d_ws;                       // 16384*1024 f16 (32MB)
  __fp16* WqT = Qh  + (size_t)16384 * 1024;          // 1024*1024 each
  __fp16* WkT = WqT + (size_t)1024 * 1024;
  __fp16* WvT = WkT + (size_t)1024 * 1024;
  __fp16* pkT = WvT + (size_t)1024 * 1024;           // 256*4096 each
  __fp16* pvT = pkT + (size_t)256 * 4096;
  __fp16* Xk  = pvT + (size_t)256 * 4096;            // 4*256*1024 each
  __fp16* Xv  = Xk  + (size_t)4 * 256 * 1024;
  __fp16* Kp  = Xv  + (size_t)4 * 256 * 1024;
  __fp16* Vpt = Kp  + (size_t)4 * 256 * 1024;
  __fp16* wsEnd = Vpt + (size_t)4 * 256 * 1024;      // = d_ws + 52,428,800 B
  // d_out scratch: Xf16 + XT (fully overwritten by attn_k at the end)
  __fp16* Xf16 = (__fp16*)d_out;                     // 4*4096*1024 f16
  __fp16* XT   = Xf16 + (size_t)4 * 4096 * 1024;     // 4*1024*4096 f16

  // Partials: layout B (own region after Vpt) if ws is big enough -> merged
  // midphase; else layout A (alias Qh region) -> serial (r17 flow).
  const size_t needB = 52428800ULL + 2ULL * 16 * 256 * 1024 * 2;  // +16MB
  const bool bigWs = (ws_size >= needB);
  __fp16* Pk16 = bigWs ? wsEnd : (__fp16*)d_ws;
  __fp16* Pv16 = Pk16 + (size_t)16 * 256 * 1024;

  const dim3 bb(256);

  // 0. all conversions in one launch
  prep<<<dim3(13312), bb, 0, stream>>>(x, Xf16, XT, Wq, Wk, Wv, WqT, WkT, WvT,
                                       pk, pv, pkT, pvT);

  if (bigWs) {
    // 1+3 merged: gemm_q + 2x-packed stage1 (independent outputs)
    midphase<<<dim3(1024), dim3(512), 0, stream>>>(Xf16, WqT, Qh, pkT, pvT, XT,
                                                   Pk16, Pv16);
    stage1_reduce<<<dim3(512), bb, 0, stream>>>(Pk16, Pv16, Xk, Xv);
    bt64z<<<dim3(512), bb, 0, stream>>>(Xk, WkT, Kp, WvT, Xv, Vpt);
  } else {
    // serial fallback (exact r17 flow)
    stage1_partial<<<dim3(1024), bb, 0, stream>>>(pkT, pvT, XT, Pk16, Pv16);
    stage1_reduce<<<dim3(512), bb, 0, stream>>>(Pk16, Pv16, Xk, Xv);
    bt64z<<<dim3(512), bb, 0, stream>>>(Xk, WkT, Kp, WvT, Xv, Vpt);
    gemm_q<<<dim3(512), dim3(512), 0, stream>>>(Xf16, WqT, Qh);
  }

  // 4. attention (overwrites Xf16/XT = d_out)
  attn_k<<<dim3(2048), bb, 0, stream>>>(Qh, Kp, Vpt, out);
}